// Round 4
// baseline (358.705 us; speedup 1.0000x reference)
//
#include <hip/hip_runtime.h>
#include <math.h>

// HMM forward (log-space, shared-max trick):
//   new_j = lp_j + M + log( sum_i exp(alpha_i - M) * P_ij ),  M = max_i alpha_i
// P = softmax(T, dim=1) is constant -> per-lane column in registers.
// Layout: lane = (seq_half, state). 2 sequences per 64-lane wave, 1 wave/block.

#define KST 32

__global__ void hmm_zero(float* out) { if (threadIdx.x == 0) out[0] = 0.f; }

__global__ __launch_bounds__(64) void hmm_fwd(
    const float* __restrict__ log_pdf,  // [32][Ntot]
    const float* __restrict__ pi,       // [32]
    const float* __restrict__ T,        // [32][32]
    float* __restrict__ out,            // [1]
    int Ntot, int Ns)
{
    const int lane = threadIdx.x;       // 0..63
    const int j    = lane & 31;         // state
    const int half = lane >> 5;         // which sequence of this wave
    const int seq  = blockIdx.x * 2 + half;

    __shared__ float rowlog[KST];       // per-row logsumexp of T
    __shared__ float evec[2][KST];      // e-vector per sequence

    // ---- init: row logsumexp of T (lanes 0..31 compute row j) ----
    if (half == 0) {
        const float* row = T + j * KST;
        float m = row[0];
        #pragma unroll
        for (int i = 1; i < KST; ++i) m = fmaxf(m, row[i]);
        float s = 0.f;
        #pragma unroll
        for (int i = 0; i < KST; ++i) s += __expf(row[i] - m);
        rowlog[j] = m + __logf(s);
    }
    __syncthreads();

    // P column j into registers: tc[i] = exp(T[i][j] - rowlog[i])
    float tc[KST];
    #pragma unroll
    for (int i = 0; i < KST; ++i)
        tc[i] = __expf(T[i * KST + j] - rowlog[i]);

    // log_softmax(pi)[j]
    float lpi;
    {
        float m = pi[0];
        #pragma unroll
        for (int i = 1; i < KST; ++i) m = fmaxf(m, pi[i]);
        float s = 0.f;
        #pragma unroll
        for (int i = 0; i < KST; ++i) s += __expf(pi[i] - m);
        lpi = pi[j] - (m + __logf(s));
    }

    // emission pointer for (state j, sequence seq): log_pdf[j][seq*Ns + t]
    const float* lpb = log_pdf + (size_t)j * (size_t)Ntot + (size_t)seq * (size_t)Ns;

    float alpha;

    // one recursion step given this lane's emission lp_t
    auto step = [&](float lp_t) {
        // group max over 32 states
        float m = alpha;
        m = fmaxf(m, __shfl_xor(m, 1, 32));
        m = fmaxf(m, __shfl_xor(m, 2, 32));
        m = fmaxf(m, __shfl_xor(m, 4, 32));
        m = fmaxf(m, __shfl_xor(m, 8, 32));
        m = fmaxf(m, __shfl_xor(m, 16, 32));
        float e = __expf(alpha - m);
        evec[half][j] = e;
        __syncthreads();   // 1 wave/block: cheap; orders write->read
        float a0 = 0.f, a1 = 0.f, a2 = 0.f, a3 = 0.f;
        const float4* ev = (const float4*)(&evec[half][0]);
        #pragma unroll
        for (int k = 0; k < 8; ++k) {
            float4 e4 = ev[k];   // broadcast read within 32-lane group
            a0 = fmaf(e4.x, tc[4 * k + 0], a0);
            a1 = fmaf(e4.y, tc[4 * k + 1], a1);
            a2 = fmaf(e4.z, tc[4 * k + 2], a2);
            a3 = fmaf(e4.w, tc[4 * k + 3], a3);
        }
        // next write to evec depends on alpha -> ordered after reads
        alpha = lp_t + m + __logf((a0 + a1) + (a2 + a3));
    };

    // t = 0 chunk (t=0..3); alpha0 = lp[t=0] + log_pi
    float4 cur = *(const float4*)lpb;
    alpha = cur.x + lpi;

    const int nchunk = Ns / 4;   // 128 for Ns=512
    for (int c = 0; c + 1 < nchunk; ++c) {
        float4 nxt = *(const float4*)(lpb + 4 * (c + 1));  // prefetch next chunk
        step(cur.y);
        step(cur.z);
        step(cur.w);
        step(nxt.x);
        cur = nxt;
    }
    // tail: t = Ns-3 .. Ns-1
    step(cur.y);
    step(cur.z);
    step(cur.w);

    // final logsumexp over states for this sequence
    float m = alpha;
    m = fmaxf(m, __shfl_xor(m, 1, 32));
    m = fmaxf(m, __shfl_xor(m, 2, 32));
    m = fmaxf(m, __shfl_xor(m, 4, 32));
    m = fmaxf(m, __shfl_xor(m, 8, 32));
    m = fmaxf(m, __shfl_xor(m, 16, 32));
    float ex = __expf(alpha - m);
    float s = ex;
    s += __shfl_xor(s, 1, 32);
    s += __shfl_xor(s, 2, 32);
    s += __shfl_xor(s, 4, 32);
    s += __shfl_xor(s, 8, 32);
    s += __shfl_xor(s, 16, 32);
    float res = m + __logf(s);            // uniform within each 32-group

    float other = __shfl_xor(res, 32, 64); // swap halves (all lanes active)
    if (lane == 0) atomicAdd(out, res + other);
}

extern "C" void kernel_launch(void* const* d_in, const int* in_sizes, int n_in,
                              void* d_out, int out_size, void* d_ws, size_t ws_size,
                              hipStream_t stream) {
    const float* log_pdf = (const float*)d_in[0];
    const float* pi      = (const float*)d_in[1];
    const float* T       = (const float*)d_in[2];
    float* out = (float*)d_out;

    const int K    = in_sizes[1];            // 32
    const int Ntot = in_sizes[0] / K;        // 1048576
    const int Ns   = 512;                    // setup_inputs constant
    const int num_seq = Ntot / Ns;           // 2048

    hmm_zero<<<1, 64, 0, stream>>>(out);
    hmm_fwd<<<num_seq / 2, 64, 0, stream>>>(log_pdf, pi, T, out, Ntot, Ns);
}

// Round 5
// 258.901 us; speedup vs baseline: 1.3855x; 1.3855x over previous
//
#include <hip/hip_runtime.h>
#include <math.h>

// HMM forward, linear-domain recursion with periodic renormalization.
//   v_j(t) = E_j(t) * sum_i v_i(t-1) * P_ij,  alpha = log v + L
//   E = exp(log_pdf) (precomputed off the dependent chain from prefetched chunk)
//   every 4 steps: m = max_j v_j (DPP+swizzle all-reduce), v *= rcp(m), L += log m
// P = softmax(T, dim=1) constant -> per-lane column in registers.
// Layout: lane = (seq_half, state). 2 sequences per 64-lane wave, 1 wave/block.

#define KST 32

// DPP row_ror:n within each 16-lane row (VALU-speed cross-lane)
#define DPP_ROR(x, n) __int_as_float(__builtin_amdgcn_update_dpp( \
    0, __float_as_int(x), 0x120 + (n), 0xF, 0xF, true))
// ds_swizzle BitMode xor 16 within each 32-lane group
#define SWZ_XOR16(x) __int_as_float(__builtin_amdgcn_ds_swizzle( \
    __float_as_int(x), 0x401F))

__device__ __forceinline__ float grpmax32(float x) {
    x = fmaxf(x, DPP_ROR(x, 1));
    x = fmaxf(x, DPP_ROR(x, 2));
    x = fmaxf(x, DPP_ROR(x, 4));
    x = fmaxf(x, DPP_ROR(x, 8));
    x = fmaxf(x, SWZ_XOR16(x));
    return x;
}
__device__ __forceinline__ float grpsum32(float x) {
    x = x + DPP_ROR(x, 1);
    x = x + DPP_ROR(x, 2);
    x = x + DPP_ROR(x, 4);
    x = x + DPP_ROR(x, 8);
    x = x + SWZ_XOR16(x);
    return x;
}

__global__ void hmm_zero(float* out) { if (threadIdx.x == 0) out[0] = 0.f; }

__global__ __launch_bounds__(64) void hmm_fwd(
    const float* __restrict__ log_pdf,  // [32][Ntot]
    const float* __restrict__ pi,       // [32]
    const float* __restrict__ T,        // [32][32]
    float* __restrict__ out,            // [1]
    int Ntot, int Ns)
{
    const int lane = threadIdx.x;       // 0..63
    const int j    = lane & 31;         // state
    const int half = lane >> 5;         // which sequence of this wave
    const int seq  = blockIdx.x * 2 + half;

    __shared__ float rowlog[KST];       // per-row logsumexp of T
    __shared__ float vvec[2][KST];      // v-vector per sequence

    // ---- init: row logsumexp of T (lanes 0..31 compute row j) ----
    if (half == 0) {
        const float* row = T + j * KST;
        float m = row[0];
        #pragma unroll
        for (int i = 1; i < KST; ++i) m = fmaxf(m, row[i]);
        float s = 0.f;
        #pragma unroll
        for (int i = 0; i < KST; ++i) s += __expf(row[i] - m);
        rowlog[j] = m + __logf(s);
    }
    __syncthreads();

    // P column j into registers: tc[i] = exp(T[i][j] - rowlog[i])
    float tc[KST];
    #pragma unroll
    for (int i = 0; i < KST; ++i)
        tc[i] = __expf(T[i * KST + j] - rowlog[i]);

    // log_softmax(pi)[j]
    float lpi;
    {
        float m = pi[0];
        #pragma unroll
        for (int i = 1; i < KST; ++i) m = fmaxf(m, pi[i]);
        float s = 0.f;
        #pragma unroll
        for (int i = 0; i < KST; ++i) s += __expf(pi[i] - m);
        lpi = pi[j] - (m + __logf(s));
    }

    // emission pointer for (state j, sequence seq): log_pdf[j][seq*Ns + t]
    const float* lpb = log_pdf + (size_t)j * (size_t)Ntot + (size_t)seq * (size_t)Ns;

    float v, L;

    // one linear-domain step; E = exp(emission at t)
    auto stepL = [&](float E) {
        vvec[half][j] = v;
        __syncthreads();   // single-wave WG: compiles to (at most) waitcnt+cheap barrier
        float a0 = 0.f, a1 = 0.f, a2 = 0.f, a3 = 0.f;
        float b0 = 0.f, b1 = 0.f, b2 = 0.f, b3 = 0.f;
        const float4* ev = (const float4*)(&vvec[half][0]);
        #pragma unroll
        for (int k = 0; k < 4; ++k) {
            float4 e4 = ev[2 * k];       // broadcast read within 32-lane group
            float4 f4 = ev[2 * k + 1];
            a0 = fmaf(e4.x, tc[8 * k + 0], a0);
            a1 = fmaf(e4.y, tc[8 * k + 1], a1);
            a2 = fmaf(e4.z, tc[8 * k + 2], a2);
            a3 = fmaf(e4.w, tc[8 * k + 3], a3);
            b0 = fmaf(f4.x, tc[8 * k + 4], b0);
            b1 = fmaf(f4.y, tc[8 * k + 5], b1);
            b2 = fmaf(f4.z, tc[8 * k + 6], b2);
            b3 = fmaf(f4.w, tc[8 * k + 7], b3);
        }
        v = (((a0 + a1) + (a2 + a3)) + ((b0 + b1) + (b2 + b3))) * E;
    };

    // ---- t = 0: alpha0 = lp[0] + log_pi, convert to linear ----
    float4 cur = *(const float4*)lpb;          // t = 0..3
    float alpha0 = cur.x + lpi;
    float m0 = grpmax32(alpha0);
    v = __expf(alpha0 - m0);
    L = m0;
    float Ea = __expf(cur.y), Eb = __expf(cur.z), Ec = __expf(cur.w);

    const int nchunk = Ns / 4;   // 128 for Ns=512
    for (int c = 0; c + 1 < nchunk; ++c) {
        float4 nxt = *(const float4*)(lpb + 4 * (c + 1));   // prefetch next chunk
        float Fa = __expf(nxt.x), Fb = __expf(nxt.y);
        float Fc = __expf(nxt.z), Fd = __expf(nxt.w);
        stepL(Ea);
        stepL(Eb);
        stepL(Ec);
        stepL(Fa);
        // renormalize every 4 steps (keeps v in fp32 range; drift bounded)
        float m = grpmax32(v);
        float r = __builtin_amdgcn_rcpf(m);
        v *= r;
        L += __logf(m);
        Ea = Fb; Eb = Fc; Ec = Fd;
    }
    // tail: t = Ns-3 .. Ns-1
    stepL(Ea);
    stepL(Eb);
    stepL(Ec);

    // final logsumexp over states: res = L + log(sum_j v_j)
    float S = grpsum32(v);
    float res = L + __logf(S);            // uniform within each 32-group

    float other = __shfl_xor(res, 32, 64); // swap halves (all lanes active)
    if (lane == 0) atomicAdd(out, res + other);
}

extern "C" void kernel_launch(void* const* d_in, const int* in_sizes, int n_in,
                              void* d_out, int out_size, void* d_ws, size_t ws_size,
                              hipStream_t stream) {
    const float* log_pdf = (const float*)d_in[0];
    const float* pi      = (const float*)d_in[1];
    const float* T       = (const float*)d_in[2];
    float* out = (float*)d_out;

    const int K    = in_sizes[1];            // 32
    const int Ntot = in_sizes[0] / K;        // 1048576
    const int Ns   = 512;                    // setup_inputs constant
    const int num_seq = Ntot / Ns;           // 2048

    hmm_zero<<<1, 64, 0, stream>>>(out);
    hmm_fwd<<<num_seq / 2, 64, 0, stream>>>(log_pdf, pi, T, out, Ntot, Ns);
}